// Round 1
// 144.942 us; speedup vs baseline: 1.0231x; 1.0231x over previous
//
#include <hip/hip_runtime.h>

#define NUM_CLASSES 80
#define BATCH 8
#define N20 1200
#define N40 4800
#define N80 19200
#define NANCH 25200
#define NEGV  -1000000000.0f
#define SCORE_THR 0.25f
#define CAP 2048            // candidate capacity (expected ~510/batch)
#define RMAX 192            // ranks materialized in the suppression matrix
#define PKCAP 512           // prefiltered participant capacity
#define NHBIN 1024          // histogram bins over the [64,128) octave
#define THR_LIST 64.0f      // candidate threshold (exact float)
#define NBLK 99             // score blocks per batch (ceil(25200/256))
#define NSLOT 396           // wave slots per batch (99 blocks * 4 waves)
#define SLOTCAP 32          // keys stored per wave slot (mean ~1.35; >32 -> exact fallback)

typedef unsigned long long ull;

// ---------------------------------------------------------------------------
// Kernel 1: class argmax + score (R10-proven) + per-wave candidate emission.
// The ballot-compaction is free: kernel is HBM-BW-bound with idle VALU, and
// it removes the entire scan phase from the NMS kernel.
// ---------------------------------------------------------------------------
__global__ __launch_bounds__(256, 3) void score_kernel(
        const float* __restrict__ p20, const float* __restrict__ c20,
        const float* __restrict__ p40, const float* __restrict__ c40,
        const float* __restrict__ p80, const float* __restrict__ c80,
        float* __restrict__ scores, unsigned* __restrict__ gcnt,
        ull* __restrict__ gkeys) {
    const int t = threadIdx.x;
    const int b = blockIdx.y;
    const int an = blockIdx.x * 256 + t;
    const bool valid_an = (an < NANCH);
    const int n = valid_an ? an : (NANCH - 1);

    const float *cp, *pp;
    if (n < N20) {
        cp = c20 + ((size_t)b * N20 + n) * NUM_CLASSES;
        pp = p20 + (size_t)b * N20 + n;
    } else if (n < N20 + N40) {
        int a = n - N20;
        cp = c40 + ((size_t)b * N40 + a) * NUM_CLASSES;
        pp = p40 + (size_t)b * N40 + a;
    } else {
        int a = n - N20 - N40;
        cp = c80 + ((size_t)b * N80 + a) * NUM_CLASSES;
        pp = p80 + (size_t)b * N80 + a;
    }

    const float4* c4 = (const float4*)cp;
    float p = *pp;
    float4 v[20];
#pragma unroll
    for (int k = 0; k < 20; k++) v[k] = c4[k];
    __builtin_amdgcn_sched_barrier(0);   // keep all 20 loads above the argmax

    float best = -INFINITY;
    int bi = 0;
#pragma unroll
    for (int k = 0; k < 20; k++) {
        int basei = k * 4;
        if (v[k].x > best) { best = v[k].x; bi = basei; }
        if (v[k].y > best) { best = v[k].y; bi = basei + 1; }
        if (v[k].z > best) { best = v[k].z; bi = basei + 2; }
        if (v[k].w > best) { best = v[k].w; bi = basei + 3; }
    }

    float s = __fmul_rn(p, (float)bi);           // exact fp32, matches np
    float sval = (s > SCORE_THR) ? s : NEGV;
    if (valid_an) scores[(size_t)b * NANCH + an] = sval;   // coalesced (fallback needs it)

    // per-wave candidate compaction into global slots — no barriers, no atomics
    const bool cand = valid_an && (sval >= THR_LIST);
    const ull mask = __ballot(cand);
    const int lane = t & 63;
    const int slot = blockIdx.x * 4 + (t >> 6);          // 0..395 within batch
    if (cand) {
        const int pos = __popcll(mask & ((1ull << lane) - 1ull));
        if (pos < SLOTCAP) {
            const ull key = ((ull)__float_as_uint(sval) << 32) |
                            (ull)(0xFFFFFFFFu - (unsigned)an);
            gkeys[(((size_t)b * NSLOT + slot) << 5) + pos] = key;
        }
    }
    if (lane == 0) gcnt[b * NSLOT + slot] = (unsigned)__popcll(mask);
}

// exact IEEE fp32 (no FMA contraction) "IoU > 0.5" — matches numpy ref
__device__ __forceinline__ bool iou_gt(const float4 A, float areaA, const float4 Bx, float areaB) {
    float ih = fmaxf(__fsub_rn(fminf(A.z, Bx.z), fmaxf(A.x, Bx.x)), 0.0f);
    float iw = fmaxf(__fsub_rn(fminf(A.w, Bx.w), fmaxf(A.y, Bx.y)), 0.0f);
    float inter = __fmul_rn(ih, iw);
    float uni = __fsub_rn(__fadd_rn(areaA, areaB), inter);
    if (!(uni > 0.0f)) return false;
    return __fdiv_rn(inter, uni) > 0.5f;
}

// Same exact predicate with a division screen: if 2*inter < uni*(1-2^-23)
// then q_rn(inter/uni) <= 0.5 provably — skip the divide. Borderline pairs
// (rare) take the exact __fdiv_rn path — bit-identical decisions to numpy.
__device__ __forceinline__ bool iou_gt_fast(const float4 A, float areaA, const float4 Bx, float areaB) {
    float ih = fmaxf(__fsub_rn(fminf(A.z, Bx.z), fmaxf(A.x, Bx.x)), 0.0f);
    float iw = fmaxf(__fsub_rn(fminf(A.w, Bx.w), fmaxf(A.y, Bx.y)), 0.0f);
    float inter = __fmul_rn(ih, iw);
    float uni = __fsub_rn(__fadd_rn(areaA, areaB), inter);
    if (!(uni > 0.0f)) return false;
    if (__fmul_rn(2.0f, inter) < __fmul_rn(uni, 0.99999988f)) return false;
    return __fdiv_rn(inter, uni) > 0.5f;
}

__device__ __forceinline__ float4 load_box(int b, int n,
        const float* b20, const float* b40, const float* b80) {
    if (n < N20)       return ((const float4*)b20)[(size_t)b * N20 + n];
    if (n < N20 + N40) return ((const float4*)b40)[(size_t)b * N40 + (n - N20)];
    return ((const float4*)b80)[(size_t)b * N80 + (n - N20 - N40)];
}

__device__ __forceinline__ float box_area(const float4 B) {
    return __fmul_rn(__fsub_rn(B.z, B.x), __fsub_rn(B.w, B.y));
}

__device__ __forceinline__ int key_idx(ull k) {
    return (int)(0xFFFFFFFFu - (unsigned)(k & 0xFFFFFFFFull));
}

// ---------------------------------------------------------------------------
// Kernel 2: exact greedy NMS. Change vs previous: the 100 KB score re-scan +
// same-address LDS atomic compaction + hist pass is replaced by a direct
// gather of the pre-compacted candidate lists (396 counts + ~530 keys).
// Key set identical; rank pass canonicalizes order — exactness unchanged.
// Slot overflow (>SLOTCAP keys in one wave) routes to the exact fallback.
// ---------------------------------------------------------------------------
__global__ __launch_bounds__(1024) void nms_kernel(
        float* __restrict__ scores, const unsigned* __restrict__ gcnt,
        const ull* __restrict__ gkeys,
        const float* __restrict__ b20, const float* __restrict__ b40,
        const float* __restrict__ b80, float* __restrict__ out) {
    __shared__ ull skeys[CAP];              // 16 KB (aliased as fallback reduce buf)
    __shared__ ull pk[PKCAP];               // 4 KB participants
    __shared__ unsigned hist[NHBIN];        // 4 KB
    __shared__ int prt[PKCAP][5];           // 10 KB (bank-padded rank partials)
    __shared__ ull srt_key[RMAX];           // 1.5 KB
    __shared__ float4 bboxC[4][RMAX + 1];   // 12.4 KB (4 bank-offset copies)
    __shared__ ull M[RMAX][3];              // 4.5 KB
    __shared__ unsigned scnt[NSLOT];        // 1.6 KB per-slot counts
    __shared__ unsigned soff[NSLOT];        // 1.6 KB exclusive offsets
    __shared__ int sh_V, sh_T, sh_m, sh_ovf;
    __shared__ unsigned sh_pcnt;

    const int t = threadIdx.x;
    const int lane = t & 63;
    const int b = blockIdx.x;

    hist[t] = 0u;                       // NHBIN == blockDim == 1024
    if (t == 0) { sh_V = 0; sh_ovf = 0; sh_pcnt = 0u; }
    __syncthreads();

    // ---- Phase A: load per-wave-slot candidate counts -------------------
    if (t < NSLOT) {
        unsigned c = gcnt[b * NSLOT + t];
        scnt[t] = c;
        if (c > (unsigned)SLOTCAP) sh_ovf = 1;   // lossy slot -> exact fallback
    }
    __syncthreads();

    // ---- Phase B: wave-0 exclusive prefix over 396 counts ---------------
    if (t < 64) {
        unsigned c[7];
        unsigned s = 0;
#pragma unroll
        for (int k = 0; k < 7; k++) {
            int idx = t * 7 + k;
            c[k] = (idx < NSLOT) ? scnt[idx] : 0u;
            s += c[k];
        }
        unsigned incl = s;
#pragma unroll
        for (int d = 1; d < 64; d <<= 1) {
            unsigned vv = __shfl_up(incl, d);
            if (t >= d) incl += vv;
        }
        unsigned base = incl - s;                 // exclusive across lanes
#pragma unroll
        for (int k = 0; k < 7; k++) {
            int idx = t * 7 + k;
            if (idx < NSLOT) soff[idx] = base;
            base += c[k];
        }
        if (t == 63) sh_m = (int)incl;            // total candidates
    }
    __syncthreads();

    const int m = sh_m;
    const bool use_list = (m <= CAP) && (sh_ovf == 0);
    const int nR = use_list ? min(m, RMAX) : 0;
    const unsigned need = (unsigned)nR;

    // ---- Phase C: gather compacted keys + build histogram ---------------
    if (use_list) {
        for (int c = t; c < m; c += 1024) {       // m ~ 530: one round
            int lo = 0, hi = NSLOT - 1;           // largest slot with soff<=c
            while (lo < hi) {
                int mid = (lo + hi + 1) >> 1;
                if (soff[mid] <= (unsigned)c) lo = mid; else hi = mid - 1;
            }
            ull k = gkeys[(((size_t)b * NSLOT + lo) << 5) + (c - soff[lo])];
            skeys[c] = k;
            unsigned sb = (unsigned)(k >> 32);
            atomicAdd(&hist[min((int)((sb - 0x42800000u) >> 13), NHBIN - 1)], 1u);
        }
    }
    __syncthreads();

    if (use_list) {
        // wave 0: suffix-sum over 1024 bins; T = max bin with suffix >= need
        if (t < 64) {
            unsigned h[16], sfx[16];
            const int basei = t * 16;
#pragma unroll
            for (int k = 0; k < 16; k++) h[k] = hist[basei + k];
            unsigned run = 0;
#pragma unroll
            for (int k = 15; k >= 0; k--) { run += h[k]; sfx[k] = run; }
            unsigned s = run;
#pragma unroll
            for (int d = 1; d < 64; d <<= 1) {
                unsigned vv = __shfl_down(s, d);
                if (t + d < 64) s += vv;
            }
            const unsigned above = s - run;
            int bestb = -1;
#pragma unroll
            for (int k = 0; k < 16; k++)
                if (sfx[k] + above >= need) bestb = basei + k;   // ascending keeps max
#pragma unroll
            for (int d = 32; d > 0; d >>= 1) {
                int o = __shfl_down(bestb, d);
                if (t + d < 64) bestb = max(bestb, o);
            }
            if (t == 0) sh_T = max(bestb, 0);
        }
        __syncthreads();
        const int T = sh_T;

        // compact participants (2 wave-aggregated rounds over skeys)
#pragma unroll
        for (int h = 0; h < 2; h++) {
            const int c = t + h * 1024;
            bool part = false;
            ull k = 0ull;
            if (c < m) {
                k = skeys[c];
                int bin = min((int)(((unsigned)(k >> 32) - 0x42800000u) >> 13), NHBIN - 1);
                part = (bin >= T);
            }
            ull mask = __ballot(part);
            if (mask != 0ull) {
                int leader = (int)(__ffsll(mask) - 1);
                unsigned basep = 0;
                if (lane == leader) basep = atomicAdd(&sh_pcnt, (unsigned)__popcll(mask));
                basep = __shfl(basep, leader);
                if (part) {
                    unsigned pos = basep + (unsigned)__popcll(mask & ((1ull << lane) - 1));
                    if (pos < (unsigned)PKCAP) pk[pos] = k;
                }
            }
        }
        __syncthreads();
        const int pm = (int)sh_pcnt;

        if (pm <= PKCAP) {
            // prefetch my participant's box (in flight during rank)
            ull kmy = 0ull;
            float4 bmy = make_float4(0.f, 0.f, 0.f, 0.f);
            if (t < pm) {
                kmy = pk[t];
                bmy = load_box(b, key_idx(kmy), b20, b40, b80);
            }
            // rank: thread (q,u) ranks pk[u], pk[u+256] over j-quarter q
            const int q = t >> 8, u = t & 255;
            const ull kA = (u < pm) ? pk[u] : 0ull;
            const ull kB = (u + 256 < pm) ? pk[u + 256] : 0ull;
            const int Q = (pm + 3) >> 2;
            const int j0 = q * Q, j1 = min(pm, j0 + Q);
            int rA = 0, rB = 0;
#pragma unroll 8
            for (int j = j0; j < j1; j++) {
                ull kj = pk[j];
                rA += (kj > kA) ? 1 : 0;
                rB += (kj > kB) ? 1 : 0;
            }
            prt[u][q] = rA;
            prt[u + 256][q] = rB;
            __syncthreads();
            if (t < pm) {
                int r = prt[t][0] + prt[t][1] + prt[t][2] + prt[t][3];
                if (r < RMAX) {
                    srt_key[r] = kmy;
#pragma unroll
                    for (int c = 0; c < 4; c++) bboxC[c][r] = bmy;
                }
            }
            __syncthreads();
        } else {
            // guard: full rank of my 2 slots over all m keys
            ull kA = (t < m) ? skeys[t] : 0ull;
            ull kB = (t + 1024 < m) ? skeys[t + 1024] : 0ull;
            int rA = 0, rB = 0;
            for (int j = 0; j < m; j++) {
                ull kj = skeys[j];
                rA += (kj > kA) ? 1 : 0;
                rB += (kj > kB) ? 1 : 0;
            }
            if (t < m && rA < RMAX) srt_key[rA] = kA;
            if (t + 1024 < m && rB < RMAX) srt_key[rB] = kB;
            __syncthreads();
            if (t < nR) {
                float4 B = load_box(b, key_idx(srt_key[t]), b20, b40, b80);
#pragma unroll
                for (int c = 0; c < 4; c++) bboxC[c][t] = B;
            }
            __syncthreads();
        }

        // suppression matrix: M[row][cw] bit j = (rank cw*64+j suppresses row)
        // bboxC bank layout: dword-bank = (4*cw + 4*j) % 32 — disjoint per cw.
        {
            const int row = t >> 2, cw = t & 3;
            if (row < RMAX && cw < 3) {
                ull w = 0ull;
                if (row < nR && cw * 64 < row) {
                    const float4 B = bboxC[cw][row];
                    const float aB = box_area(B);
                    const int jmax = min(64, row - cw * 64);
                    const float4* src = &bboxC[cw][cw * 64];
                    for (int j = 0; j < jmax; j++) {
                        const float4 C = src[j];
                        w |= ((ull)iou_gt_fast(C, box_area(C), B, aB)) << j;
                    }
                }
                M[row][cw] = w;
            }
        }
        __syncthreads();

        // greedy resolution: wave 0, accepted-set in registers (pure VALU)
        int v = 0;
        if (t < 64) {
            ull A0 = 0, A1 = 0, A2 = 0;
            for (int rg = 0; rg < 3 && v < 100; rg++) {
                const int rr = rg * 64 + t;
                const bool valid = (rr < nR);
                ull w0 = 0, w1 = 0, w2 = 0;
                if (valid) { w0 = M[rr][0]; w1 = M[rr][1]; w2 = M[rr][2]; }
                const ull mw = (rg == 0) ? w0 : (rg == 1) ? w1 : w2;
                const bool supE = !valid ||
                    (((w0 & A0) | (w1 & A1) | (w2 & A2)) != 0ull);
                ull alive = __ballot(!supE);
                while (alive != 0ull && v < 100) {
                    int c = (int)(__ffsll(alive) - 1);
                    ull supc = __ballot((bool)((mw >> c) & 1ull));
                    alive &= ~(supc | (1ull << c));
                    if (rg == 0) A0 |= 1ull << c;
                    else if (rg == 1) A1 |= 1ull << c;
                    else A2 |= 1ull << c;
                    if (t == c) {
                        const float4 B = bboxC[0][rr];
                        float* rowp = out + ((size_t)b * 100 + v) * 6;
                        rowp[0] = fminf(fmaxf(B.x, 0.f), 1.f);
                        rowp[1] = fminf(fmaxf(B.y, 0.f), 1.f);
                        rowp[2] = fminf(fmaxf(B.z, 0.f), 1.f);
                        rowp[3] = fminf(fmaxf(B.w, 0.f), 1.f);
                        rowp[4] = __uint_as_float((unsigned)(srt_key[rr] >> 32));
                        rowp[5] = 0.f;
                    }
                    v++;
                }
            }
            if (t == 0) sh_V = v;
        }
        __syncthreads();
    }

    // ------- exact fallback: reference-style greedy (never taken here) -----
    // Safer trigger than before: ANY sh_V<100 re-runs the full exact greedy
    // (reference would continue accepting sub-THR_LIST boxes).
    const bool need_fb = (!use_list) || (sh_V < 100);
    if (need_fb) {
        ull* red = skeys;                       // alias: skeys no longer needed
        float* scb = scores + (size_t)b * NANCH;
        int v2 = 0;
        for (int k = 0; k < 100; k++) {
            ull bestk = 0ull;
            for (int i = t; i < NANCH; i += 1024) {
                float sv = scb[i];
                unsigned u = __float_as_uint(sv);
                u ^= (u & 0x80000000u) ? 0xFFFFFFFFu : 0x80000000u;
                ull key = ((ull)u << 32) | (ull)(0xFFFFFFFFu - (unsigned)i);
                if (key > bestk) bestk = key;
            }
            red[t] = bestk;
            __syncthreads();
            for (int ss = 512; ss > 0; ss >>= 1) {
                if (t < ss && red[t + ss] > red[t]) red[t] = red[t + ss];
                __syncthreads();
            }
            ull bk = red[0];
            __syncthreads();
            unsigned u = (unsigned)(bk >> 32);
            u ^= (u & 0x80000000u) ? 0x80000000u : 0xFFFFFFFFu;
            float s = __uint_as_float(u);
            int idx = (int)(0xFFFFFFFFu - (unsigned)(bk & 0xFFFFFFFFull));
            if (!(s > NEGV * 0.5f)) break;                  // wave-uniform
            float4 B = load_box(b, idx, b20, b40, b80);
            float aB = box_area(B);
            for (int i = t; i < NANCH; i += 1024) {
                float sv = scb[i];
                if (sv > NEGV * 0.5f) {
                    float4 C = load_box(b, i, b20, b40, b80);
                    if (iou_gt(B, aB, C, box_area(C))) scb[i] = NEGV;
                }
            }
            if (t == 0) {
                scb[idx] = NEGV;
                float* rowp = out + ((size_t)b * 100 + k) * 6;
                rowp[0] = fminf(fmaxf(B.x, 0.f), 1.f);
                rowp[1] = fminf(fmaxf(B.y, 0.f), 1.f);
                rowp[2] = fminf(fmaxf(B.z, 0.f), 1.f);
                rowp[3] = fminf(fmaxf(B.w, 0.f), 1.f);
                rowp[4] = s;
                rowp[5] = 0.f;
            }
            v2++;
            __syncthreads();
        }
        __syncthreads();
        if (t == 0) sh_V = v2;
        __syncthreads();
    }

    const int V = sh_V;
    for (int i = V * 6 + t; i < 600; i += 1024) out[(size_t)b * 600 + i] = 0.f;
    if (t == 0) out[4800 + b] = (float)V;
}

extern "C" void kernel_launch(void* const* d_in, const int* in_sizes, int n_in,
                              void* d_out, int out_size, void* d_ws, size_t ws_size,
                              hipStream_t stream) {
    const float* b20 = (const float*)d_in[0];
    const float* p20 = (const float*)d_in[1];
    const float* c20 = (const float*)d_in[2];
    const float* b40 = (const float*)d_in[3];
    const float* p40 = (const float*)d_in[4];
    const float* c40 = (const float*)d_in[5];
    const float* b80 = (const float*)d_in[6];
    const float* p80 = (const float*)d_in[7];
    const float* c80 = (const float*)d_in[8];

    // ws layout: scores 806400 B | gcnt 12672 B | gkeys 811008 B  (~1.6 MB)
    float*    scores = (float*)d_ws;
    unsigned* gcnt   = (unsigned*)((char*)d_ws + 806400);
    ull*      gkeys  = (ull*)((char*)d_ws + 806400 + 12672);

    dim3 sgrid((NANCH + 255) / 256, BATCH);
    score_kernel<<<sgrid, 256, 0, stream>>>(
        p20, c20, p40, c40, p80, c80, scores, gcnt, gkeys);

    nms_kernel<<<BATCH, 1024, 0, stream>>>(
        scores, gcnt, gkeys, b20, b40, b80, (float*)d_out);
}

// Round 3
// 132.137 us; speedup vs baseline: 1.1223x; 1.0969x over previous
//
#include <hip/hip_runtime.h>

#define NUM_CLASSES 80
#define BATCH 8
#define N20 1200
#define N40 4800
#define N80 19200
#define NANCH 25200
#define NEGV  -1000000000.0f
#define SCORE_THR 0.25f
#define CAP 2048            // candidate capacity (expected ~510/batch)
#define RMAX 192            // ranks materialized in the suppression matrix
#define PKCAP 512           // prefiltered participant capacity
#define NHBIN 1024          // histogram bins over the [64,128) octave
#define THR_LIST 64.0f      // candidate threshold (exact float)
#define NBLK 99             // score blocks per batch (ceil(25200/256))
#define NSLOT 396           // wave slots per batch (99 blocks * 4 waves)
#define SLOTCAP 32          // keys stored per wave slot (mean ~1.35; >32 -> exact fallback)

typedef unsigned long long ull;

// ---------------------------------------------------------------------------
// Kernel 1: class argmax + score (R10-proven) + per-wave candidate emission.
// ---------------------------------------------------------------------------
__global__ __launch_bounds__(256, 3) void score_kernel(
        const float* __restrict__ p20, const float* __restrict__ c20,
        const float* __restrict__ p40, const float* __restrict__ c40,
        const float* __restrict__ p80, const float* __restrict__ c80,
        float* __restrict__ scores, unsigned* __restrict__ gcnt,
        ull* __restrict__ gkeys) {
    const int t = threadIdx.x;
    const int b = blockIdx.y;
    const int an = blockIdx.x * 256 + t;
    const bool valid_an = (an < NANCH);
    const int n = valid_an ? an : (NANCH - 1);

    const float *cp, *pp;
    if (n < N20) {
        cp = c20 + ((size_t)b * N20 + n) * NUM_CLASSES;
        pp = p20 + (size_t)b * N20 + n;
    } else if (n < N20 + N40) {
        int a = n - N20;
        cp = c40 + ((size_t)b * N40 + a) * NUM_CLASSES;
        pp = p40 + (size_t)b * N40 + a;
    } else {
        int a = n - N20 - N40;
        cp = c80 + ((size_t)b * N80 + a) * NUM_CLASSES;
        pp = p80 + (size_t)b * N80 + a;
    }

    const float4* c4 = (const float4*)cp;
    float p = *pp;
    float4 v[20];
#pragma unroll
    for (int k = 0; k < 20; k++) v[k] = c4[k];
    __builtin_amdgcn_sched_barrier(0);   // keep all 20 loads above the argmax

    float best = -INFINITY;
    int bi = 0;
#pragma unroll
    for (int k = 0; k < 20; k++) {
        int basei = k * 4;
        if (v[k].x > best) { best = v[k].x; bi = basei; }
        if (v[k].y > best) { best = v[k].y; bi = basei + 1; }
        if (v[k].z > best) { best = v[k].z; bi = basei + 2; }
        if (v[k].w > best) { best = v[k].w; bi = basei + 3; }
    }

    float s = __fmul_rn(p, (float)bi);           // exact fp32, matches np
    float sval = (s > SCORE_THR) ? s : NEGV;
    if (valid_an) scores[(size_t)b * NANCH + an] = sval;   // coalesced (fallback needs it)

    // per-wave candidate compaction into global slots — no barriers, no atomics
    const bool cand = valid_an && (sval >= THR_LIST);
    const ull mask = __ballot(cand);
    const int lane = t & 63;
    const int slot = blockIdx.x * 4 + (t >> 6);          // 0..395 within batch
    if (cand) {
        const int pos = __popcll(mask & ((1ull << lane) - 1ull));
        if (pos < SLOTCAP) {
            const ull key = ((ull)__float_as_uint(sval) << 32) |
                            (ull)(0xFFFFFFFFu - (unsigned)an);
            gkeys[(((size_t)b * NSLOT + slot) << 5) + pos] = key;
        }
    }
    if (lane == 0) gcnt[b * NSLOT + slot] = (unsigned)__popcll(mask);
}

// exact IEEE fp32 (no FMA contraction) "IoU > 0.5" — matches numpy ref
__device__ __forceinline__ bool iou_gt(const float4 A, float areaA, const float4 Bx, float areaB) {
    float ih = fmaxf(__fsub_rn(fminf(A.z, Bx.z), fmaxf(A.x, Bx.x)), 0.0f);
    float iw = fmaxf(__fsub_rn(fminf(A.w, Bx.w), fmaxf(A.y, Bx.y)), 0.0f);
    float inter = __fmul_rn(ih, iw);
    float uni = __fsub_rn(__fadd_rn(areaA, areaB), inter);
    if (!(uni > 0.0f)) return false;
    return __fdiv_rn(inter, uni) > 0.5f;
}

// Same exact predicate with a division screen — bit-identical decisions.
__device__ __forceinline__ bool iou_gt_fast(const float4 A, float areaA, const float4 Bx, float areaB) {
    float ih = fmaxf(__fsub_rn(fminf(A.z, Bx.z), fmaxf(A.x, Bx.x)), 0.0f);
    float iw = fmaxf(__fsub_rn(fminf(A.w, Bx.w), fmaxf(A.y, Bx.y)), 0.0f);
    float inter = __fmul_rn(ih, iw);
    float uni = __fsub_rn(__fadd_rn(areaA, areaB), inter);
    if (!(uni > 0.0f)) return false;
    if (__fmul_rn(2.0f, inter) < __fmul_rn(uni, 0.99999988f)) return false;
    return __fdiv_rn(inter, uni) > 0.5f;
}

__device__ __forceinline__ float4 load_box(int b, int n,
        const float* b20, const float* b40, const float* b80) {
    if (n < N20)       return ((const float4*)b20)[(size_t)b * N20 + n];
    if (n < N20 + N40) return ((const float4*)b40)[(size_t)b * N40 + (n - N20)];
    return ((const float4*)b80)[(size_t)b * N80 + (n - N20 - N40)];
}

__device__ __forceinline__ float box_area(const float4 B) {
    return __fmul_rn(__fsub_rn(B.z, B.x), __fsub_rn(B.w, B.y));
}

__device__ __forceinline__ int key_idx(ull k) {
    return (int)(0xFFFFFFFFu - (unsigned)(k & 0xFFFFFFFFull));
}

// ---------------------------------------------------------------------------
// Kernel 2: exact greedy NMS. Changes vs R1:
//  (a) suppression matrix built in balanced 32-bit halfwords (192*6=1152
//      units over 1024 threads; crit path 64->~36 IoU evals). M32[.][7]
//      stride-7 keeps greedy's reads 2-way-conflict-free.
//  (b) greedy resolution: wave-parallel FIXPOINT per 64-rank group (~3-6
//      rounds of 2 ballots) instead of ~100 serially-dependent accept
//      iterations; output slots via popcount prefix, stores in parallel.
//      Accept set provably identical to sequential greedy. Guarded: if the
//      fixpoint ever fails to converge in 64 rounds (unreachable), route to
//      the exact fallback instead of storing.
// ---------------------------------------------------------------------------
__global__ __launch_bounds__(1024) void nms_kernel(
        float* __restrict__ scores, const unsigned* __restrict__ gcnt,
        const ull* __restrict__ gkeys,
        const float* __restrict__ b20, const float* __restrict__ b40,
        const float* __restrict__ b80, float* __restrict__ out) {
    __shared__ ull skeys[CAP];              // 16 KB (aliased as fallback reduce buf)
    __shared__ ull pk[PKCAP];               // 4 KB participants
    __shared__ unsigned hist[NHBIN];        // 4 KB
    __shared__ int prt[PKCAP][5];           // 10 KB (bank-padded rank partials)
    __shared__ ull srt_key[RMAX];           // 1.5 KB
    __shared__ float4 bboxC[4][RMAX + 1];   // 12.4 KB (4 bank-offset copies)
    __shared__ unsigned M32[RMAX][7];       // 5.25 KB (6 words + stride-7 pad)
    __shared__ unsigned scnt[NSLOT];        // 1.6 KB per-slot counts
    __shared__ unsigned soff[NSLOT];        // 1.6 KB exclusive offsets
    __shared__ int sh_V, sh_T, sh_m, sh_ovf;
    __shared__ unsigned sh_pcnt;

    const int t = threadIdx.x;
    const int lane = t & 63;
    const int b = blockIdx.x;

    hist[t] = 0u;                       // NHBIN == blockDim == 1024
    if (t == 0) { sh_V = 0; sh_ovf = 0; sh_pcnt = 0u; }
    __syncthreads();

    // ---- Phase A: load per-wave-slot candidate counts -------------------
    if (t < NSLOT) {
        unsigned c = gcnt[b * NSLOT + t];
        scnt[t] = c;
        if (c > (unsigned)SLOTCAP) sh_ovf = 1;   // lossy slot -> exact fallback
    }
    __syncthreads();

    // ---- Phase B: wave-0 exclusive prefix over 396 counts ---------------
    if (t < 64) {
        unsigned c[7];
        unsigned s = 0;
#pragma unroll
        for (int k = 0; k < 7; k++) {
            int idx = t * 7 + k;
            c[k] = (idx < NSLOT) ? scnt[idx] : 0u;
            s += c[k];
        }
        unsigned incl = s;
#pragma unroll
        for (int d = 1; d < 64; d <<= 1) {
            unsigned vv = __shfl_up(incl, d);
            if (t >= d) incl += vv;
        }
        unsigned base = incl - s;                 // exclusive across lanes
#pragma unroll
        for (int k = 0; k < 7; k++) {
            int idx = t * 7 + k;
            if (idx < NSLOT) soff[idx] = base;
            base += c[k];
        }
        if (t == 63) sh_m = (int)incl;            // total candidates
    }
    __syncthreads();

    const int m = sh_m;
    const bool use_list = (m <= CAP) && (sh_ovf == 0);
    const int nR = use_list ? min(m, RMAX) : 0;
    const unsigned need = (unsigned)nR;

    // ---- Phase C: gather compacted keys + build histogram ---------------
    if (use_list) {
        for (int c = t; c < m; c += 1024) {       // m ~ 530: one round
            int lo = 0, hi = NSLOT - 1;           // largest slot with soff<=c
            while (lo < hi) {
                int mid = (lo + hi + 1) >> 1;
                if (soff[mid] <= (unsigned)c) lo = mid; else hi = mid - 1;
            }
            ull k = gkeys[(((size_t)b * NSLOT + lo) << 5) + (c - soff[lo])];
            skeys[c] = k;
            unsigned sb = (unsigned)(k >> 32);
            atomicAdd(&hist[min((int)((sb - 0x42800000u) >> 13), NHBIN - 1)], 1u);
        }
    }
    __syncthreads();

    if (use_list) {
        // wave 0: suffix-sum over 1024 bins; T = max bin with suffix >= need
        if (t < 64) {
            unsigned h[16], sfx[16];
            const int basei = t * 16;
#pragma unroll
            for (int k = 0; k < 16; k++) h[k] = hist[basei + k];
            unsigned run = 0;
#pragma unroll
            for (int k = 15; k >= 0; k--) { run += h[k]; sfx[k] = run; }
            unsigned s = run;
#pragma unroll
            for (int d = 1; d < 64; d <<= 1) {
                unsigned vv = __shfl_down(s, d);
                if (t + d < 64) s += vv;
            }
            const unsigned above = s - run;
            int bestb = -1;
#pragma unroll
            for (int k = 0; k < 16; k++)
                if (sfx[k] + above >= need) bestb = basei + k;   // ascending keeps max
#pragma unroll
            for (int d = 32; d > 0; d >>= 1) {
                int o = __shfl_down(bestb, d);
                if (t + d < 64) bestb = max(bestb, o);
            }
            if (t == 0) sh_T = max(bestb, 0);
        }
        __syncthreads();
        const int T = sh_T;

        // compact participants (2 wave-aggregated rounds over skeys)
#pragma unroll
        for (int h = 0; h < 2; h++) {
            const int c = t + h * 1024;
            bool part = false;
            ull k = 0ull;
            if (c < m) {
                k = skeys[c];
                int bin = min((int)(((unsigned)(k >> 32) - 0x42800000u) >> 13), NHBIN - 1);
                part = (bin >= T);
            }
            ull mask = __ballot(part);
            if (mask != 0ull) {
                int leader = (int)(__ffsll(mask) - 1);
                unsigned basep = 0;
                if (lane == leader) basep = atomicAdd(&sh_pcnt, (unsigned)__popcll(mask));
                basep = __shfl(basep, leader);
                if (part) {
                    unsigned pos = basep + (unsigned)__popcll(mask & ((1ull << lane) - 1));
                    if (pos < (unsigned)PKCAP) pk[pos] = k;
                }
            }
        }
        __syncthreads();
        const int pm = (int)sh_pcnt;

        if (pm <= PKCAP) {
            // prefetch my participant's box (in flight during rank)
            ull kmy = 0ull;
            float4 bmy = make_float4(0.f, 0.f, 0.f, 0.f);
            if (t < pm) {
                kmy = pk[t];
                bmy = load_box(b, key_idx(kmy), b20, b40, b80);
            }
            // rank: thread (q,u) ranks pk[u], pk[u+256] over j-quarter q
            const int q = t >> 8, u = t & 255;
            const ull kA = (u < pm) ? pk[u] : 0ull;
            const ull kB = (u + 256 < pm) ? pk[u + 256] : 0ull;
            const int Q = (pm + 3) >> 2;
            const int j0 = q * Q, j1 = min(pm, j0 + Q);
            int rA = 0, rB = 0;
#pragma unroll 8
            for (int j = j0; j < j1; j++) {
                ull kj = pk[j];
                rA += (kj > kA) ? 1 : 0;
                rB += (kj > kB) ? 1 : 0;
            }
            prt[u][q] = rA;
            prt[u + 256][q] = rB;
            __syncthreads();
            if (t < pm) {
                int r = prt[t][0] + prt[t][1] + prt[t][2] + prt[t][3];
                if (r < RMAX) {
                    srt_key[r] = kmy;
#pragma unroll
                    for (int c = 0; c < 4; c++) bboxC[c][r] = bmy;
                }
            }
            __syncthreads();
        } else {
            // guard: full rank of my 2 slots over all m keys
            ull kA = (t < m) ? skeys[t] : 0ull;
            ull kB = (t + 1024 < m) ? skeys[t + 1024] : 0ull;
            int rA = 0, rB = 0;
            for (int j = 0; j < m; j++) {
                ull kj = skeys[j];
                rA += (kj > kA) ? 1 : 0;
                rB += (kj > kB) ? 1 : 0;
            }
            if (t < m && rA < RMAX) srt_key[rA] = kA;
            if (t + 1024 < m && rB < RMAX) srt_key[rB] = kB;
            __syncthreads();
            if (t < nR) {
                float4 B = load_box(b, key_idx(srt_key[t]), b20, b40, b80);
#pragma unroll
                for (int c = 0; c < 4; c++) bboxC[c][t] = B;
            }
            __syncthreads();
        }

        // suppression matrix, balanced halfwords: unit e=(row,hw), hw in [0,6).
        // M32[row][hw] bit j = (rank hw*32+j suppresses row), hw*32+j < row.
        for (int e = t; e < RMAX * 6; e += 1024) {
            const int row = e / 6, hw = e - row * 6;
            unsigned wbits = 0u;
            const int j0 = hw * 32;
            if (row < nR && j0 < row) {
                const int cw = hw >> 1;                  // bank-offset copy
                const float4 B = bboxC[cw][row];
                const float aB = box_area(B);
                const int jmax = min(32, row - j0);
                const float4* src = &bboxC[cw][j0];
                for (int j = 0; j < jmax; j++) {
                    const float4 C = src[j];
                    wbits |= ((unsigned)iou_gt_fast(C, box_area(C), B, aB)) << j;
                }
            }
            M32[row][hw] = wbits;
        }
        __syncthreads();

        // greedy resolution: wave-parallel fixpoint per 64-rank group.
        // Exactness: a row is greedy-accepted iff no accepted lower-ranked
        // suppressor exists. Per round, undecided rows with an accepted
        // suppressor reject; rows whose in-group suppressors are all decided
        // (and none accepted, incl. prior groups via P) accept. The lowest
        // undecided lane always decides each round (its matrix bits are all
        // < its own lane index) -> Um strictly shrinks -> terminates.
        if (t < 64) {
            ull Af0 = 0ull, Af1 = 0ull, Af2 = 0ull;
            bool fail = false;
#pragma unroll
            for (int rg = 0; rg < 3; rg++) {
                const int rr = rg * 64 + t;
                const ull w0 = (ull)M32[rr][0] | ((ull)M32[rr][1] << 32);
                const ull w1 = (ull)M32[rr][2] | ((ull)M32[rr][3] << 32);
                const ull w2 = (ull)M32[rr][4] | ((ull)M32[rr][5] << 32);
                const ull mw = (rg == 0) ? w0 : (rg == 1) ? w1 : w2;
                ull P = 0ull;
                if (rg >= 1) P |= (w0 & Af0);
                if (rg >= 2) P |= (w1 & Af1);
                const bool valid = (rr < nR);
                bool acc = false;
                bool und = valid && (P == 0ull);
                ull Ag = 0ull;
                ull Um = __ballot(und);
                int guard = 64;                       // defensive bound
                while (Um != 0ull && guard-- > 0) {
                    if (und) {
                        if ((mw & Ag) != 0ull) und = false;            // rejected
                        else if ((mw & Um) == 0ull) { acc = true; und = false; }
                    }
                    Ag = __ballot(acc);
                    Um = __ballot(und);
                }
                if (Um != 0ull) fail = true;          // unreachable by proof
                if (rg == 0) Af0 = Ag; else if (rg == 1) Af1 = Ag; else Af2 = Ag;
            }
            const int c0 = __popcll(Af0), c1 = __popcll(Af1);
            const int total = c0 + c1 + __popcll(Af2);
            const ull low = (1ull << t) - 1ull;
            if (!fail) {
#pragma unroll
                for (int rg = 0; rg < 3; rg++) {
                    const ull Af = (rg == 0) ? Af0 : (rg == 1) ? Af1 : Af2;
                    if ((Af >> t) & 1ull) {
                        const int v = ((rg >= 1) ? c0 : 0) + ((rg >= 2) ? c1 : 0) +
                                      __popcll(Af & low);
                        if (v < 100) {
                            const int rr = rg * 64 + t;
                            const float4 B = bboxC[0][rr];
                            float* rowp = out + ((size_t)b * 100 + v) * 6;
                            rowp[0] = fminf(fmaxf(B.x, 0.f), 1.f);
                            rowp[1] = fminf(fmaxf(B.y, 0.f), 1.f);
                            rowp[2] = fminf(fmaxf(B.z, 0.f), 1.f);
                            rowp[3] = fminf(fmaxf(B.w, 0.f), 1.f);
                            rowp[4] = __uint_as_float((unsigned)(srt_key[rr] >> 32));
                            rowp[5] = 0.f;
                        }
                    }
                }
            }
            if (t == 0) sh_V = fail ? 0 : ((total < 100) ? total : 100);
        }
        __syncthreads();
    }

    // ------- exact fallback: reference-style greedy (never taken here) -----
    const bool need_fb = (!use_list) || (sh_V < 100);
    if (need_fb) {
        ull* red = skeys;                       // alias: skeys no longer needed
        float* scb = scores + (size_t)b * NANCH;
        int v2 = 0;
        for (int k = 0; k < 100; k++) {
            ull bestk = 0ull;
            for (int i = t; i < NANCH; i += 1024) {
                float sv = scb[i];
                unsigned u = __float_as_uint(sv);
                u ^= (u & 0x80000000u) ? 0xFFFFFFFFu : 0x80000000u;
                ull key = ((ull)u << 32) | (ull)(0xFFFFFFFFu - (unsigned)i);
                if (key > bestk) bestk = key;
            }
            red[t] = bestk;
            __syncthreads();
            for (int ss = 512; ss > 0; ss >>= 1) {
                if (t < ss && red[t + ss] > red[t]) red[t] = red[t + ss];
                __syncthreads();
            }
            ull bk = red[0];
            __syncthreads();
            unsigned u = (unsigned)(bk >> 32);
            u ^= (u & 0x80000000u) ? 0x80000000u : 0xFFFFFFFFu;
            float s = __uint_as_float(u);
            int idx = (int)(0xFFFFFFFFu - (unsigned)(bk & 0xFFFFFFFFull));
            if (!(s > NEGV * 0.5f)) break;                  // wave-uniform
            float4 B = load_box(b, idx, b20, b40, b80);
            float aB = box_area(B);
            for (int i = t; i < NANCH; i += 1024) {
                float sv = scb[i];
                if (sv > NEGV * 0.5f) {
                    float4 C = load_box(b, i, b20, b40, b80);
                    if (iou_gt(B, aB, C, box_area(C))) scb[i] = NEGV;
                }
            }
            if (t == 0) {
                scb[idx] = NEGV;
                float* rowp = out + ((size_t)b * 100 + k) * 6;
                rowp[0] = fminf(fmaxf(B.x, 0.f), 1.f);
                rowp[1] = fminf(fmaxf(B.y, 0.f), 1.f);
                rowp[2] = fminf(fmaxf(B.z, 0.f), 1.f);
                rowp[3] = fminf(fmaxf(B.w, 0.f), 1.f);
                rowp[4] = s;
                rowp[5] = 0.f;
            }
            v2++;
            __syncthreads();
        }
        __syncthreads();
        if (t == 0) sh_V = v2;
        __syncthreads();
    }

    const int V = sh_V;
    for (int i = V * 6 + t; i < 600; i += 1024) out[(size_t)b * 600 + i] = 0.f;
    if (t == 0) out[4800 + b] = (float)V;
}

extern "C" void kernel_launch(void* const* d_in, const int* in_sizes, int n_in,
                              void* d_out, int out_size, void* d_ws, size_t ws_size,
                              hipStream_t stream) {
    const float* b20 = (const float*)d_in[0];
    const float* p20 = (const float*)d_in[1];
    const float* c20 = (const float*)d_in[2];
    const float* b40 = (const float*)d_in[3];
    const float* p40 = (const float*)d_in[4];
    const float* c40 = (const float*)d_in[5];
    const float* b80 = (const float*)d_in[6];
    const float* p80 = (const float*)d_in[7];
    const float* c80 = (const float*)d_in[8];

    // ws layout: scores 806400 B | gcnt 12672 B | gkeys 811008 B  (~1.6 MB)
    float*    scores = (float*)d_ws;
    unsigned* gcnt   = (unsigned*)((char*)d_ws + 806400);
    ull*      gkeys  = (ull*)((char*)d_ws + 806400 + 12672);

    dim3 sgrid((NANCH + 255) / 256, BATCH);
    score_kernel<<<sgrid, 256, 0, stream>>>(
        p20, c20, p40, c40, p80, c80, scores, gcnt, gkeys);

    nms_kernel<<<BATCH, 1024, 0, stream>>>(
        scores, gcnt, gkeys, b20, b40, b80, (float*)d_out);
}